// Round 11
// baseline (26.164 us; speedup 1.0000x reference)
//
#include <hip/hip_runtime.h>
#include <math.h>

#define NSAMP 32
#define HW 512
#define PW 128
#define NPOOL (PW * PW)                 // 16384 pooled elements / sample
#define BPS 16                          // blocks per sample
#define NBLOCKS (NSAMP * BPS)           // 512 (2 blocks / CU, all co-resident)
#define PPT 4                           // pooled patches per thread
#define NACC 14

// ws layout: ws[0] = u64 rendezvous counter (never reset; alignment-free logic)
//            part floats start at byte 64: part[k * NBLOCKS + bid]
// acc layout: 0 bce(log2) 1 mask_cnt 2 intersection 3 label_sum
// 4 S_v 5 S_h 6 S_l 7 S_vv 8 S_hh 9 S_ll 10 S_vh 11 S_vl 12 S_hl 13 S_vhl

// full-wave (64 lane) sum via DPP on the VALU pipe; result valid in lane 63
__device__ __forceinline__ float wave_sum_dpp(float x) {
#define DPP_ADD(ctrl)                                                         \
    x += __int_as_float(__builtin_amdgcn_update_dpp(                          \
        0, __float_as_int(x), (ctrl), 0xf, 0xf, true));
    DPP_ADD(0x111)   // row_shr:1
    DPP_ADD(0x112)   // row_shr:2
    DPP_ADD(0x114)   // row_shr:4
    DPP_ADD(0x118)   // row_shr:8
    DPP_ADD(0x142)   // row_bcast:15
    DPP_ADD(0x143)   // row_bcast:31 -> lane 63 = full 64-lane sum
#undef DPP_ADD
    return x;
}

__global__ __launch_bounds__(256, 2) void covloss_fused(
    const float* __restrict__ logits, const float* __restrict__ labels,
    const float* __restrict__ v_att,  const float* __restrict__ h_att,
    float* __restrict__ out, unsigned long long* __restrict__ ws)
{
    unsigned long long* counter = ws;
    float* part = (float*)(ws + 8);          // 64B offset

    // --- read rendezvous base FIRST (all blocks start ~simultaneously;
    //     first increment happens only after a full block's work ~10+ us later)
    unsigned long long s0 = 0;
    if (threadIdx.x == 0)
        s0 = __hip_atomic_load(counter, __ATOMIC_RELAXED, __HIP_MEMORY_SCOPE_AGENT);

    const int bid   = blockIdx.x;
    const int n     = bid >> 4;              // sample
    const int local = bid & 15;              // block within sample
    const int pbase = local * (PPT * 256);

    const float* lg = logits + (size_t)n * HW * HW;
    const float* lb = labels + (size_t)n * HW * HW;
    const float* va = v_att + (size_t)n * NPOOL;
    const float* ha = h_att + (size_t)n * NPOOL;

    float bce = 0.f, inter = 0.f, ysum = 0.f;
    unsigned long long cnt_u = 0;            // wave-uniform via ballot (SALU)
    float S_v = 0.f, S_h = 0.f, S_l = 0.f;
    float S_vv = 0.f, S_hh = 0.f, S_ll = 0.f;
    float S_vh = 0.f, S_vl = 0.f, S_hl = 0.f, S_vhl = 0.f;

    // three named prefetch buffers (all indices compile-time -> registers)
    float4 PA[4], YA[4]; float vA, hA;
    float4 PB[4], YB[4]; float vB, hB;
    float4 PC[4], YC[4]; float vC, hC;

#define LOADBUF(S, p) {                                                       \
    const int pidx = pbase + (p) * 256 + (int)threadIdx.x;                    \
    const int pr = pidx >> 7, pc = pidx & 127;                                \
    const float4* lg4 = (const float4*)(lg + (size_t)(4 * pr) * HW) + pc;     \
    const float4* lb4 = (const float4*)(lb + (size_t)(4 * pr) * HW) + pc;     \
    P##S[0] = lg4[0]; P##S[1] = lg4[HW / 4];                                  \
    P##S[2] = lg4[2 * (HW / 4)]; P##S[3] = lg4[3 * (HW / 4)];                 \
    Y##S[0] = lb4[0]; Y##S[1] = lb4[HW / 4];                                  \
    Y##S[2] = lb4[2 * (HW / 4)]; Y##S[3] = lb4[3 * (HW / 4)];                 \
    v##S = va[pidx]; h##S = ha[pidx]; }

#define COMPUTE(S) {                                                          \
    float lsum = 0.f;                                                         \
    _Pragma("unroll")                                                         \
    for (int i = 0; i < 4; ++i) {                                             \
        const float pv[4] = {P##S[i].x, P##S[i].y, P##S[i].z, P##S[i].w};     \
        const float yv[4] = {Y##S[i].x, Y##S[i].y, Y##S[i].z, Y##S[i].w};     \
        _Pragma("unroll")                                                     \
        for (int j = 0; j < 4; ++j) {                                         \
            const float pp = pv[j], y = yv[j];                                \
            bce = fmaf(y, __log2f(pp), bce);                                  \
            bce = fmaf(1.f - y, __log2f(1.f - pp), bce);                      \
            const bool m = pp > 0.4f;                                         \
            cnt_u += __popcll(__ballot(m));                                   \
            inter += m ? y : 0.f;                                             \
            lsum  += y;                                                       \
        }                                                                     \
    }                                                                         \
    ysum += lsum;                                                             \
    const float l = lsum * 0.0625f;                                           \
    const float v = v##S, h = h##S;                                           \
    S_v += v; S_h += h; S_l += l;                                             \
    S_vv = fmaf(v, v, S_vv); S_hh = fmaf(h, h, S_hh); S_ll = fmaf(l, l, S_ll);\
    const float vh = v * h;                                                   \
    S_vh += vh; S_vl = fmaf(v, l, S_vl); S_hl = fmaf(h, l, S_hl);             \
    S_vhl = fmaf(vh, l, S_vhl); }

    // depth-2 software pipeline: loads for p+1, p+2 in flight during compute(p)
    LOADBUF(A, 0)
    LOADBUF(B, 1)
    LOADBUF(C, 2)
    COMPUTE(A)
    LOADBUF(A, 3)
    COMPUTE(B)
    COMPUTE(C)
    COMPUTE(A)

#undef LOADBUF
#undef COMPUTE

    // 13 lane-varying accumulators; cnt_u is wave-uniform
    float vals[13] = { bce, inter, ysum,
                       S_v, S_h, S_l, S_vv, S_hh, S_ll,
                       S_vh, S_vl, S_hl, S_vhl };
#pragma unroll
    for (int k = 0; k < 13; ++k) vals[k] = wave_sum_dpp(vals[k]);

    __shared__ float sh[4][NACC];
    const int lane = threadIdx.x & 63, wv = threadIdx.x >> 6;
    if (lane == 63) {
        sh[wv][0] = vals[0];
        sh[wv][1] = (float)cnt_u;
        sh[wv][2] = vals[1];
        sh[wv][3] = vals[2];
#pragma unroll
        for (int k = 3; k < 13; ++k) sh[wv][k + 1] = vals[k];
    }
    __syncthreads();

    // publish partials: relaxed agent-scope stores (write-through to coherent
    // point — no cache-maintenance, no zero-init since slots are overwritten)
    if (threadIdx.x < NACC) {
        const float p = sh[0][threadIdx.x] + sh[1][threadIdx.x] +
                        sh[2][threadIdx.x] + sh[3][threadIdx.x];
        __hip_atomic_store(&part[(size_t)threadIdx.x * NBLOCKS + bid], p,
                           __ATOMIC_RELAXED, __HIP_MEMORY_SCOPE_AGENT);
    }

    // rendezvous: wave 0 drains its own stores (vmcnt ack at coherent point),
    // then bumps the never-reset counter. Last arrival: old == s0 + NBLOCKS-1.
    __shared__ int lastflag;
    if (threadIdx.x == 0) {
        __builtin_amdgcn_s_waitcnt(0);
        const unsigned long long old = __hip_atomic_fetch_add(
            counter, 1ULL, __ATOMIC_RELAXED, __HIP_MEMORY_SCOPE_AGENT);
        lastflag = (old == s0 + (NBLOCKS - 1));
    }
    __syncthreads();
    if (!lastflag) return;

    // ---- finalize: exactly one block; reads all partials via agent loads ----
    const int t = threadIdx.x;
    __shared__ double acc[NSAMP][NACC];
    for (int pair = t; pair < NSAMP * NACC; pair += 256) {
        const int s = pair / NACC, k = pair % NACC;
        const float* p = part + (size_t)k * NBLOCKS + s * BPS;
        double a = 0.0;
#pragma unroll
        for (int i = 0; i < BPS; ++i)
            a += (double)__hip_atomic_load(p + i, __ATOMIC_RELAXED,
                                           __HIP_MEMORY_SCOPE_AGENT);
        acc[s][k] = a;
    }
    __syncthreads();

    __shared__ double sb[NSAMP], sd[NSAMP], sc[NSAMP];
    if (t < NSAMP) {
        const double* a = acc[t];
        const double nn = (double)NPOOL;
        const double cvv = a[7] - a[4] * a[4] / nn;
        const double chh = a[8] - a[5] * a[5] / nn;
        const double cll = a[9] - a[6] * a[6] / nn;
        const double num = a[13]
            - (a[4] * a[12] + a[5] * a[11] + a[6] * a[10]) / nn
            + 2.0 * a[4] * a[5] * a[6] / (nn * nn);
        sc[t] = num / sqrt(cvv * chh * cll);
        sd[t] = 2.0 * (a[2] + 1.0) / (a[1] + a[3] + 1.0);
        sb[t] = a[0];
    }
    __syncthreads();
    if (t == 0) {
        double bces = 0.0, ds = 0.0, cs = 0.0;
#pragma unroll
        for (int i = 0; i < NSAMP; ++i) { bces += sb[i]; ds += sd[i]; cs += sc[i]; }
        const double bceloss = -(bces * M_LN2) / ((double)NSAMP * HW * HW);
        out[0] = (float)(0.2 * bceloss + 0.3 * (1.0 - ds / NSAMP) + 0.5 * (-cs / NSAMP));
    }
}

extern "C" void kernel_launch(void* const* d_in, const int* in_sizes, int n_in,
                              void* d_out, int out_size, void* d_ws, size_t ws_size,
                              hipStream_t stream) {
    const float* logits = (const float*)d_in[0];
    const float* labels = (const float*)d_in[1];
    const float* v_att  = (const float*)d_in[2];
    const float* h_att  = (const float*)d_in[3];
    float* out = (float*)d_out;
    unsigned long long* ws = (unsigned long long*)d_ws;

    covloss_fused<<<NBLOCKS, 256, 0, stream>>>(logits, labels, v_att, h_att, out, ws);
}

// Round 14
// 22.398 us; speedup vs baseline: 1.1681x; 1.1681x over previous
//
#include <hip/hip_runtime.h>
#include <math.h>

#define NSAMP 32
#define HW 512
#define PW 128
#define NPOOL (PW * PW)                 // 16384 pooled elements / sample
#define BPS 16                          // blocks per sample
#define NBLOCKS (NSAMP * BPS)           // 512 (2 blocks / CU) — measured sweet spot
#define PPT 4                           // pooled patches per thread
#define NACC 14

// acc layout: 0 bce(log2) 1 mask_cnt 2 intersection 3 label_sum
// 4 S_v 5 S_h 6 S_l 7 S_vv 8 S_hh 9 S_ll 10 S_vh 11 S_vl 12 S_hl 13 S_vhl
// part transposed: part[k * NBLOCKS + bid]

#define AS1 __attribute__((address_space(1)))
#define AS3 __attribute__((address_space(3)))

// async global->LDS DMA, 16B per lane; LDS dest wave-uniform base + lane*16
__device__ __forceinline__ void g2l16(const float* g, float* l) {
    __builtin_amdgcn_global_load_lds((const AS1 void*)g, (AS3 void*)l, 16, 0, 0);
}

#define FENCE()   do { asm volatile("" ::: "memory"); } while (0)
#define WAITV(n)  do { asm volatile("s_waitcnt vmcnt(" #n ")" ::: "memory"); } while (0)

// full-wave (64 lane) sum via DPP on the VALU pipe; result valid in lane 63
__device__ __forceinline__ float wave_sum_dpp(float x) {
#define DPP_ADD(ctrl)                                                         \
    x += __int_as_float(__builtin_amdgcn_update_dpp(                          \
        0, __float_as_int(x), (ctrl), 0xf, 0xf, true));
    DPP_ADD(0x111)   // row_shr:1
    DPP_ADD(0x112)   // row_shr:2
    DPP_ADD(0x114)   // row_shr:4
    DPP_ADD(0x118)   // row_shr:8
    DPP_ADD(0x142)   // row_bcast:15
    DPP_ADD(0x143)   // row_bcast:31 -> lane 63 = full 64-lane sum
#undef DPP_ADD
    return x;
}

__global__ __launch_bounds__(256) void covloss_main(
    const float* __restrict__ logits, const float* __restrict__ labels,
    const float* __restrict__ v_att,  const float* __restrict__ h_att,
    float* __restrict__ part)
{
    // [buf(2)][L/Y(2)][wave(4)][row(4)][lane(64)][4 floats] = 64 KB
    __shared__ __align__(16) float lds[16384];

    const int bid   = blockIdx.x;
    const int n     = bid >> 4;              // sample
    const int local = bid & 15;              // block within sample
    const int pbase = local * (PPT * 256);
    const int tid   = threadIdx.x;
    const int wv    = tid >> 6, lane = tid & 63;

    const float* lg = logits + (size_t)n * HW * HW;
    const float* lb = labels + (size_t)n * HW * HW;
    const float* va = v_att + (size_t)n * NPOOL;
    const float* ha = h_att + (size_t)n * NPOOL;

    float bce = 0.f, inter = 0.f, ysum = 0.f;
    unsigned long long cnt_u = 0;            // wave-uniform via ballot (SALU)
    float S_v = 0.f, S_h = 0.f, S_l = 0.f;
    float S_vv = 0.f, S_hh = 0.f, S_ll = 0.f;
    float S_vh = 0.f, S_vl = 0.f, S_hl = 0.f, S_vhl = 0.f;

    // wave-private LDS region: no cross-wave sharing -> no barriers in main loop
#define STAGE(b, p) do {                                                      \
    const int pidx = pbase + (p) * 256 + tid;                                 \
    const int pr = pidx >> 7, pc = pidx & 127;                                \
    const float* gl = lg + (size_t)(4 * pr) * HW + 4 * pc;                    \
    const float* gy = lb + (size_t)(4 * pr) * HW + 4 * pc;                    \
    float* dl = &lds[(b) * 8192 + wv * 1024];                                 \
    float* dy = &lds[(b) * 8192 + 4096 + wv * 1024];                          \
    g2l16(gl,          dl);        g2l16(gl + HW,     dl + 256);              \
    g2l16(gl + 2 * HW, dl + 512);  g2l16(gl + 3 * HW, dl + 768);              \
    g2l16(gy,          dy);        g2l16(gy + HW,     dy + 256);              \
    g2l16(gy + 2 * HW, dy + 512);  g2l16(gy + 3 * HW, dy + 768);              \
} while (0)

#define COMPUTE(b, vS, hS) do {                                               \
    const float4* Lp = (const float4*)&lds[(b) * 8192 + wv * 1024];           \
    const float4* Yp = (const float4*)&lds[(b) * 8192 + 4096 + wv * 1024];    \
    float lsum = 0.f;                                                         \
    _Pragma("unroll")                                                         \
    for (int i = 0; i < 4; ++i) {                                             \
        const float4 p4 = Lp[i * 64 + lane];                                  \
        const float4 y4 = Yp[i * 64 + lane];                                  \
        const float pv[4] = {p4.x, p4.y, p4.z, p4.w};                         \
        const float yv[4] = {y4.x, y4.y, y4.z, y4.w};                         \
        _Pragma("unroll")                                                     \
        for (int j = 0; j < 4; ++j) {                                         \
            const float pp = pv[j], y = yv[j];                                \
            bce = fmaf(y, __log2f(pp), bce);                                  \
            bce = fmaf(1.f - y, __log2f(1.f - pp), bce);                      \
            const bool m = pp > 0.4f;                                         \
            cnt_u += __popcll(__ballot(m));                                   \
            inter += m ? y : 0.f;                                             \
            lsum  += y;                                                       \
        }                                                                     \
    }                                                                         \
    ysum += lsum;                                                             \
    const float l = lsum * 0.0625f;                                           \
    S_v += vS; S_h += hS; S_l += l;                                           \
    S_vv = fmaf(vS, vS, S_vv); S_hh = fmaf(hS, hS, S_hh);                     \
    S_ll = fmaf(l, l, S_ll);                                                  \
    const float vh = vS * hS;                                                 \
    S_vh += vh; S_vl = fmaf(vS, l, S_vl); S_hl = fmaf(hS, l, S_hl);           \
    S_vhl = fmaf(vh, l, S_vhl);                                               \
} while (0)

    // prologue: v/h for all 4 patches (8 VMEM), then stage patches 0,1
    const int px0 = pbase + tid, px1 = px0 + 256, px2 = px0 + 512, px3 = px0 + 768;
    const float v0 = va[px0], h0 = ha[px0];
    const float v1 = va[px1], h1 = ha[px1];
    const float v2 = va[px2], h2 = ha[px2];
    const float v3 = va[px3], h3 = ha[px3];
    FENCE();
    STAGE(0, 0); FENCE();
    STAGE(1, 1); FENCE();

    WAITV(8);              // vh(8) + stage0(8) retired; stage1 in flight
    COMPUTE(0, v0, h0);    // patch 0 from buf 0
    FENCE();
    STAGE(0, 2); FENCE();  // restage buf 0 with patch 2 (reads already done)
    WAITV(8);              // stage1 retired; stage2 in flight
    COMPUTE(1, v1, h1);    // patch 1 from buf 1
    FENCE();
    STAGE(1, 3); FENCE();  // restage buf 1 with patch 3
    WAITV(8);              // stage2 retired; stage3 in flight
    COMPUTE(0, v2, h2);    // patch 2 from buf 0   (was the R13 bug: read buf 2!)
    WAITV(0);              // stage3 retired
    COMPUTE(1, v3, h3);    // patch 3 from buf 1

#undef STAGE
#undef COMPUTE

    // 13 lane-varying accumulators; cnt_u is wave-uniform
    float vals[13] = { bce, inter, ysum,
                       S_v, S_h, S_l, S_vv, S_hh, S_ll,
                       S_vh, S_vl, S_hl, S_vhl };
#pragma unroll
    for (int k = 0; k < 13; ++k) vals[k] = wave_sum_dpp(vals[k]);

    __shared__ float sh[4][NACC];
    if (lane == 63) {
        sh[wv][0] = vals[0];
        sh[wv][1] = (float)cnt_u;
        sh[wv][2] = vals[1];
        sh[wv][3] = vals[2];
#pragma unroll
        for (int k = 3; k < 13; ++k) sh[wv][k + 1] = vals[k];
    }
    __syncthreads();
    if (tid < NACC) {
        part[(size_t)tid * NBLOCKS + bid] =
            sh[0][tid] + sh[1][tid] + sh[2][tid] + sh[3][tid];
    }
}

__global__ __launch_bounds__(256) void covloss_finalize(
    const float* __restrict__ part, float* __restrict__ out)
{
    const int t = threadIdx.x;
    __shared__ double acc[NSAMP][NACC];

    // 448 (sample, moment) pairs; each = sum of BPS=16 contiguous floats
    for (int pair = t; pair < NSAMP * NACC; pair += 256) {
        const int s = pair / NACC, k = pair % NACC;
        const float4* p = (const float4*)(part + (size_t)k * NBLOCKS + s * BPS);
        double a = 0.0;
#pragma unroll
        for (int i = 0; i < 4; ++i) {
            const float4 q = p[i];
            a += (double)q.x + (double)q.y + (double)q.z + (double)q.w;
        }
        acc[s][k] = a;
    }
    __syncthreads();

    __shared__ double sb[NSAMP], sd[NSAMP], sc[NSAMP];
    if (t < NSAMP) {
        const double* a = acc[t];
        const double nn = (double)NPOOL;
        const double cvv = a[7] - a[4] * a[4] / nn;
        const double chh = a[8] - a[5] * a[5] / nn;
        const double cll = a[9] - a[6] * a[6] / nn;
        const double num = a[13]
            - (a[4] * a[12] + a[5] * a[11] + a[6] * a[10]) / nn
            + 2.0 * a[4] * a[5] * a[6] / (nn * nn);
        sc[t] = num / sqrt(cvv * chh * cll);
        sd[t] = 2.0 * (a[2] + 1.0) / (a[1] + a[3] + 1.0);
        sb[t] = a[0];
    }
    __syncthreads();
    if (t == 0) {
        double bces = 0.0, ds = 0.0, cs = 0.0;
#pragma unroll
        for (int i = 0; i < NSAMP; ++i) { bces += sb[i]; ds += sd[i]; cs += sc[i]; }
        const double bceloss = -(bces * M_LN2) / ((double)NSAMP * HW * HW);
        out[0] = (float)(0.2 * bceloss + 0.3 * (1.0 - ds / NSAMP) + 0.5 * (-cs / NSAMP));
    }
}

extern "C" void kernel_launch(void* const* d_in, const int* in_sizes, int n_in,
                              void* d_out, int out_size, void* d_ws, size_t ws_size,
                              hipStream_t stream) {
    const float* logits = (const float*)d_in[0];
    const float* labels = (const float*)d_in[1];
    const float* v_att  = (const float*)d_in[2];
    const float* h_att  = (const float*)d_in[3];
    float* out  = (float*)d_out;
    float* part = (float*)d_ws;   // NACC * NBLOCKS floats = 28 KB

    covloss_main<<<NBLOCKS, 256, 0, stream>>>(logits, labels, v_att, h_att, part);
    covloss_finalize<<<1, 256, 0, stream>>>(part, out);
}

// Round 15
// 20.428 us; speedup vs baseline: 1.2808x; 1.0964x over previous
//
#include <hip/hip_runtime.h>
#include <math.h>

#define NSAMP 32
#define HW 512
#define PW 128
#define NPOOL (PW * PW)                 // 16384 pooled elements / sample
#define BPS 16                          // blocks per sample
#define NBLOCKS (NSAMP * BPS)           // 512 (2 blocks / CU) — measured sweet spot
#define PPT 4                           // pooled patches per thread
#define NACC 14

typedef float f32x4 __attribute__((ext_vector_type(4)));

// two 16B loads from one base (rows r, r+1 of a 512-float row pitch)
__device__ __forceinline__ void gload2x4(f32x4& r0, f32x4& r1, const float* p) {
    asm volatile("global_load_dwordx4 %0, %2, off\n\t"
                 "global_load_dwordx4 %1, %2, off offset:2048"
                 : "=v"(r0), "=v"(r1) : "v"(p) : "memory");
}
// four scalar loads at +0,+1024,+2048,+3072 bytes
__device__ __forceinline__ void gload4(float& a, float& b, float& c, float& d,
                                       const float* p) {
    asm volatile("global_load_dword %0, %4, off\n\t"
                 "global_load_dword %1, %4, off offset:1024\n\t"
                 "global_load_dword %2, %4, off offset:2048\n\t"
                 "global_load_dword %3, %4, off offset:3072"
                 : "=v"(a), "=v"(b), "=v"(c), "=v"(d) : "v"(p) : "memory");
}

#define WAITV(n)  do { asm volatile("s_waitcnt vmcnt(" #n ")" ::: "memory"); \
                       __builtin_amdgcn_sched_barrier(0); } while (0)

// full-wave (64 lane) sum via DPP on the VALU pipe; result valid in lane 63
__device__ __forceinline__ float wave_sum_dpp(float x) {
#define DPP_ADD(ctrl)                                                         \
    x += __int_as_float(__builtin_amdgcn_update_dpp(                          \
        0, __float_as_int(x), (ctrl), 0xf, 0xf, true));
    DPP_ADD(0x111)
    DPP_ADD(0x112)
    DPP_ADD(0x114)
    DPP_ADD(0x118)
    DPP_ADD(0x142)
    DPP_ADD(0x143)
#undef DPP_ADD
    return x;
}

__global__ __launch_bounds__(256) void covloss_main(
    const float* __restrict__ logits, const float* __restrict__ labels,
    const float* __restrict__ v_att,  const float* __restrict__ h_att,
    float* __restrict__ part)
{
    const int bid   = blockIdx.x;
    const int n     = bid >> 4;              // sample
    const int local = bid & 15;              // block within sample
    const int pbase = local * (PPT * 256);
    const int tid   = threadIdx.x;

    const float* lg = logits + (size_t)n * HW * HW;
    const float* lb = labels + (size_t)n * HW * HW;

    float bce = 0.f, inter = 0.f, ysum = 0.f;
    unsigned long long cnt_u = 0;            // wave-uniform via ballot (SALU)
    float S_v = 0.f, S_h = 0.f, S_l = 0.f;
    float S_vv = 0.f, S_hh = 0.f, S_ll = 0.f;
    float S_vh = 0.f, S_vl = 0.f, S_hl = 0.f, S_vhl = 0.f;

    // two named register buffer sets (A, B): 8 f32x4 each
    f32x4 LA0, LA1, LA2, LA3, YA0, YA1, YA2, YA3;
    f32x4 LB0, LB1, LB2, LB3, YB0, YB1, YB2, YB3;
    float v0, v1, v2, v3, h0, h1, h2, h3;

#define STAGE(S, p) do {                                                      \
    const int pidx = pbase + (p) * 256 + tid;                                 \
    const int pr = pidx >> 7, pc = pidx & 127;                                \
    const float* baL = lg + (size_t)(4 * pr) * HW + 4 * pc;                   \
    const float* baY = lb + (size_t)(4 * pr) * HW + 4 * pc;                   \
    gload2x4(L##S##0, L##S##1, baL);                                          \
    gload2x4(L##S##2, L##S##3, baL + 2 * HW);                                 \
    gload2x4(Y##S##0, Y##S##1, baY);                                          \
    gload2x4(Y##S##2, Y##S##3, baY + 2 * HW);                                 \
} while (0)

#define ROW(Lr, Yr) do {                                                      \
    _Pragma("unroll")                                                         \
    for (int j = 0; j < 4; ++j) {                                             \
        const float pp = (Lr)[j], y = (Yr)[j];                                \
        bce = fmaf(y, __log2f(pp), bce);                                      \
        bce = fmaf(1.f - y, __log2f(1.f - pp), bce);                          \
        const bool m = pp > 0.4f;                                             \
        cnt_u += __popcll(__ballot(m));                                       \
        inter += m ? y : 0.f;                                                 \
        lsum  += y;                                                           \
    }                                                                         \
} while (0)

#define COMPUTE(S, vS, hS) do {                                               \
    float lsum = 0.f;                                                         \
    ROW(L##S##0, Y##S##0); ROW(L##S##1, Y##S##1);                             \
    ROW(L##S##2, Y##S##2); ROW(L##S##3, Y##S##3);                             \
    ysum += lsum;                                                             \
    const float l = lsum * 0.0625f;                                           \
    S_v += vS; S_h += hS; S_l += l;                                           \
    S_vv = fmaf(vS, vS, S_vv); S_hh = fmaf(hS, hS, S_hh);                     \
    S_ll = fmaf(l, l, S_ll);                                                  \
    const float vh = vS * hS;                                                 \
    S_vh += vh; S_vl = fmaf(vS, l, S_vl); S_hl = fmaf(hS, l, S_hl);           \
    S_vhl = fmaf(vh, l, S_vhl);                                               \
} while (0)

    // --- prologue: 8 scalar vh loads + patches 0,1 (24 VMEM in flight) ---
    gload4(v0, v1, v2, v3, v_att + (size_t)n * NPOOL + pbase + tid);
    gload4(h0, h1, h2, h3, h_att + (size_t)n * NPOOL + pbase + tid);
    STAGE(A, 0);
    STAGE(B, 1);

    WAITV(8);            // vh + patch0 retired; patch1 in flight
    COMPUTE(A, v0, h0);
    STAGE(A, 2);         // reuse A regs (dead) for patch2
    WAITV(8);            // patch1 retired; patch2 in flight
    COMPUTE(B, v1, h1);
    STAGE(B, 3);
    WAITV(8);            // patch2 retired; patch3 in flight
    COMPUTE(A, v2, h2);
    WAITV(0);            // patch3 retired
    COMPUTE(B, v3, h3);

#undef STAGE
#undef ROW
#undef COMPUTE

    // 13 lane-varying accumulators; cnt_u is wave-uniform
    float vals[13] = { bce, inter, ysum,
                       S_v, S_h, S_l, S_vv, S_hh, S_ll,
                       S_vh, S_vl, S_hl, S_vhl };
#pragma unroll
    for (int k = 0; k < 13; ++k) vals[k] = wave_sum_dpp(vals[k]);

    __shared__ float sh[4][NACC];
    const int lane = tid & 63, wv = tid >> 6;
    if (lane == 63) {
        sh[wv][0] = vals[0];
        sh[wv][1] = (float)cnt_u;
        sh[wv][2] = vals[1];
        sh[wv][3] = vals[2];
#pragma unroll
        for (int k = 3; k < 13; ++k) sh[wv][k + 1] = vals[k];
    }
    __syncthreads();
    if (tid < NACC) {
        part[(size_t)tid * NBLOCKS + bid] =
            sh[0][tid] + sh[1][tid] + sh[2][tid] + sh[3][tid];
    }
}

__global__ __launch_bounds__(256) void covloss_finalize(
    const float* __restrict__ part, float* __restrict__ out)
{
    const int t = threadIdx.x;
    __shared__ double acc[NSAMP][NACC];

    // 448 (sample, moment) pairs; each = sum of BPS=16 contiguous floats
    for (int pair = t; pair < NSAMP * NACC; pair += 256) {
        const int s = pair / NACC, k = pair % NACC;
        const float4* p = (const float4*)(part + (size_t)k * NBLOCKS + s * BPS);
        double a = 0.0;
#pragma unroll
        for (int i = 0; i < 4; ++i) {
            const float4 q = p[i];
            a += (double)q.x + (double)q.y + (double)q.z + (double)q.w;
        }
        acc[s][k] = a;
    }
    __syncthreads();

    __shared__ double sb[NSAMP], sd[NSAMP], sc[NSAMP];
    if (t < NSAMP) {
        const double* a = acc[t];
        const double nn = (double)NPOOL;
        const double cvv = a[7] - a[4] * a[4] / nn;
        const double chh = a[8] - a[5] * a[5] / nn;
        const double cll = a[9] - a[6] * a[6] / nn;
        const double num = a[13]
            - (a[4] * a[12] + a[5] * a[11] + a[6] * a[10]) / nn
            + 2.0 * a[4] * a[5] * a[6] / (nn * nn);
        sc[t] = num / sqrt(cvv * chh * cll);
        sd[t] = 2.0 * (a[2] + 1.0) / (a[1] + a[3] + 1.0);
        sb[t] = a[0];
    }
    __syncthreads();
    if (t == 0) {
        double bces = 0.0, ds = 0.0, cs = 0.0;
#pragma unroll
        for (int i = 0; i < NSAMP; ++i) { bces += sb[i]; ds += sd[i]; cs += sc[i]; }
        const double bceloss = -(bces * M_LN2) / ((double)NSAMP * HW * HW);
        out[0] = (float)(0.2 * bceloss + 0.3 * (1.0 - ds / NSAMP) + 0.5 * (-cs / NSAMP));
    }
}

extern "C" void kernel_launch(void* const* d_in, const int* in_sizes, int n_in,
                              void* d_out, int out_size, void* d_ws, size_t ws_size,
                              hipStream_t stream) {
    const float* logits = (const float*)d_in[0];
    const float* labels = (const float*)d_in[1];
    const float* v_att  = (const float*)d_in[2];
    const float* h_att  = (const float*)d_in[3];
    float* out  = (float*)d_out;
    float* part = (float*)d_ws;   // NACC * NBLOCKS floats = 28 KB

    covloss_main<<<NBLOCKS, 256, 0, stream>>>(logits, labels, v_att, h_att, part);
    covloss_finalize<<<1, 256, 0, stream>>>(part, out);
}